// Round 13
// baseline (389.350 us; speedup 1.0000x reference)
//
#include <hip/hip_runtime.h>
#include <cmath>

// Problem constants
#define B4   4
#define TT   4
#define HH   32
#define WW   16
#define LL   2048          // T*H*W
#define NCH  64            // scan chunks
#define CLEN 32            // steps per chunk
#define MEG  1048576

// ---------- fast fp64 transcendentals (rel err ~1e-13, fits 1e-9/stage budget) ----------
__device__ __forceinline__ double expd_fast(double x){
  if (x < -708.0) return 0.0;
  const double LOG2E = 1.4426950408889634074;
  const double LN2HI = 6.93147180369123816490e-01;
  const double LN2LO = 1.90821492927058770002e-10;
  double kd = rint(x*LOG2E);
  double r  = fma(-kd, LN2HI, x);
  r = fma(-kd, LN2LO, r);
  double p = 2.7557319223985888e-07;            // 1/10!
  p = fma(p, r, 2.7557319223985890e-06);
  p = fma(p, r, 2.4801587301587302e-05);
  p = fma(p, r, 1.9841269841269841e-04);
  p = fma(p, r, 1.3888888888888889e-03);
  p = fma(p, r, 8.3333333333333333e-03);
  p = fma(p, r, 4.1666666666666664e-02);
  p = fma(p, r, 1.6666666666666666e-01);
  p = fma(p, r, 5.0e-01);
  p = fma(p, r, 1.0);
  p = fma(p, r, 1.0);
  long long ki = (long long)(1023 + (int)kd) << 52;
  return p * __longlong_as_double(ki);
}
__device__ __forceinline__ double silu_fast(double a){
  return a / (1.0 + expd_fast(-a));
}
__device__ __forceinline__ double softplus_fast(double x){
  double t = expd_fast(x);
  if (t < 0.04){                                 // dominant path (dacc ~ -4.6)
    double p = 1.0/7.0;
    p = 1.0/6.0 - t*p; p = 1.0/5.0 - t*p; p = 1.0/4.0 - t*p;
    p = 1.0/3.0 - t*p; p = 1.0/2.0 - t*p; p = 1.0 - t*p;
    return t*p;                                  // log1p(t), err ~2e-11 rel
  }
  if (x > 20.0) return x;
  return log1p(t);
}

// ---------------- prep: transpose weights to fp64 + exp(Alog) table ----------------
__global__ void k_prep(const float* __restrict__ w_in, const float* __restrict__ w2,
                       const float* __restrict__ xpw, const float* __restrict__ dtw,
                       const float* __restrict__ moutw, const float* __restrict__ outw,
                       const float* __restrict__ Alog,
                       double* __restrict__ winT, double* __restrict__ w2T,
                       double* __restrict__ xpT, double* __restrict__ dtT,
                       double* __restrict__ moutT, double* __restrict__ outT,
                       double* __restrict__ ENT){
  int i = blockIdx.x*256 + threadIdx.x;
  if (i < 256*64)  winT[(i%64)*256 + i/64]   = (double)w_in[i];   // [64][256]
  if (i < 512*128) w2T[(i%128)*512 + i/128]  = (double)w2[i];     // [128][512]
  if (i < 40*256)  xpT[(i%256)*40 + i/256]   = (double)xpw[i];    // [256][40]
  if (i < 256*8)   dtT[(i%8)*256 + i/8]      = (double)dtw[i];    // [8][256]
  if (i < 128*256) moutT[(i%256)*128 + i/256]= (double)moutw[i];  // [256][128]
  if (i < 64*128)  outT[(i%128)*64 + i/128]  = (double)outw[i];   // [128][64]
  if (i < 16*256){ int n = i>>8, d = i&255; ENT[i] = exp((double)Alog[d*16+n]); } // en[n][d]
}

// ---------------- 1: in_proj (8192 tok, 64 -> 256), 8-tok tiles, transposed LDS ----------------
__global__ void k_inproj(const float* __restrict__ x, const double* __restrict__ winT,
                         float* __restrict__ xc, float* __restrict__ zo){
  __shared__ float xs[64*13];                 // [c][t], pad 13 (odd stride: conflict-free writes)
  int blk = blockIdx.x, tid = threadIdx.x;
  const float* xrow = x + (size_t)blk*8*64;
  for (int i=tid; i<8*64; i+=256){ int t=i>>6, c=i&63; xs[c*13+t] = xrow[i]; }
  __syncthreads();
  double acc[8];
  #pragma unroll
  for (int t=0;t<8;t++) acc[t]=0.0;
  for (int c=0;c<64;c++){
    double w = winT[c*256+tid];
    #pragma unroll
    for (int t=0;t<8;t++) acc[t] = fma(w, (double)xs[c*13+t], acc[t]);  // LDS broadcast
  }
  int tok0 = blk*8;
  if (tid < 128){
    #pragma unroll
    for (int t=0;t<8;t++) xc[(size_t)(tok0+t)*128 + tid] = (float)acc[t];
  } else {
    int e = tid-128;
    #pragma unroll
    for (int t=0;t<8;t++) zo[(size_t)(tok0+t)*128 + e] = (float)silu_fast(acc[t]);
  }
}

// ---------------- 2: depthwise conv3d 3x3x3 pad1 + silu ----------------
__global__ void k_conv3d(const float* __restrict__ xc, const float* __restrict__ w,
                         const float* __restrict__ bias, float* __restrict__ seq){
  int blk = blockIdx.x;
  int h = blk % HH; int t = (blk/HH) % TT; int b = blk/(HH*TT);
  int c = threadIdx.x;
  double wr[27];
  #pragma unroll
  for (int i=0;i<27;i++) wr[i] = (double)w[c*27+i];
  double bv = (double)bias[c];
  const float* base = xc + (size_t)b*LL*128;
  for (int wx=0; wx<WW; wx++){
    double acc = bv;
    #pragma unroll
    for (int dt=0; dt<3; dt++){
      int tt = t+dt-1; if (tt<0||tt>TT-1) continue;
      #pragma unroll
      for (int dh=0; dh<3; dh++){
        int h2 = h+dh-1; if (h2<0||h2>HH-1) continue;
        #pragma unroll
        for (int dw=0; dw<3; dw++){
          int w2 = wx+dw-1; if (w2<0||w2>WW-1) continue;
          int l = (tt*HH+h2)*WW+w2;
          acc = fma(wr[(dt*3+dh)*3+dw], (double)base[(size_t)l*128+c], acc);
        }
      }
    }
    int l = (t*HH+h)*WW+wx;
    seq[((size_t)b*LL+l)*128+c] = (float)silu_fast(acc);
  }
}

// ---------------- 3: m_in_proj (8192 tok, 128 -> 512), 8-tok tiles, transposed LDS ----------------
__global__ void k_minproj(const float* __restrict__ seq, const double* __restrict__ w2T,
                          float* __restrict__ upre, float* __restrict__ zm){
  __shared__ float xs[128*13];                // [c][t], pad 13
  int blk = blockIdx.x, tid = threadIdx.x;
  const float* srow = seq + (size_t)blk*8*128;
  for (int i=tid; i<8*128; i+=256){ int t=i>>7, c=i&127; xs[c*13+t] = srow[i]; }
  __syncthreads();
  double a0[8], a1[8];
  #pragma unroll
  for (int t=0;t<8;t++){a0[t]=0.0;a1[t]=0.0;}
  for (int c=0;c<128;c++){
    double w0 = w2T[c*512+tid];
    double w1 = w2T[c*512+tid+256];
    #pragma unroll
    for (int t=0;t<8;t++){
      double xv = (double)xs[c*13+t];          // LDS broadcast
      a0[t]=fma(w0,xv,a0[t]); a1[t]=fma(w1,xv,a1[t]);
    }
  }
  int tok0=blk*8;
  #pragma unroll
  for (int t=0;t<8;t++){
    upre[(size_t)(tok0+t)*256+tid] = (float)a0[t];
    zm [(size_t)(tok0+t)*256+tid] = (float)silu_fast(a1[t]);   // store gate = silu(z)
  }
}

// ---------------- 4: token-parallel front-end: conv1d+silu, x_proj, dt_proj+softplus ----------------
__global__ void k_udelta(const float* __restrict__ upre,
                         const float* __restrict__ c1w, const float* __restrict__ c1b,
                         const double* __restrict__ xpT, const double* __restrict__ dtT,
                         const float* __restrict__ dtb,
                         float* __restrict__ U, float* __restrict__ DELTA,
                         float* __restrict__ BCb){
  __shared__ float us[16*256];
  __shared__ double xdbl[16*40];
  int tile = blockIdx.x, db = blockIdx.y;
  int dir = db>>2, b = db&3;
  int d = threadIdx.x;
  double w0=(double)c1w[d*4+0], w1=(double)c1w[d*4+1], w2=(double)c1w[d*4+2], w3=(double)c1w[d*4+3];
  double cbv=(double)c1b[d];
  double dtbv=(double)dtb[d];
  double dtw[8];
  #pragma unroll
  for (int r=0;r<8;r++) dtw[r] = dtT[r*256+d];
  int l0 = tile*16;
  auto src = [&](int l)->double{
    if (l < 0) return 0.0;
    int lo = dir ? (LL-1-l) : l;
    return (double)upre[((size_t)b*LL+lo)*256+d];
  };
  double x0=src(l0-3), x1=src(l0-2), x2=src(l0-1);
  for (int i=0;i<16;i++){
    double x3 = src(l0+i);
    double a = cbv + w0*x0 + w1*x1 + w2*x2 + w3*x3;
    float uv = (float)silu_fast(a);
    us[i*256+d] = uv;
    U[((size_t)db*LL + l0+i)*256 + d] = uv;
    x0=x1; x1=x2; x2=x3;
  }
  __syncthreads();
  // x_proj GEMM (256 -> 40) for 16 tokens
  {
    int j = d & 63, grp = d >> 6;
    if (j < 40){
      double acc[4]={0.0,0.0,0.0,0.0};
      for (int c=0;c<256;c++){
        double wv = xpT[c*40+j];
        #pragma unroll
        for (int i2=0;i2<4;i2++) acc[i2] = fma(wv, (double)us[(grp*4+i2)*256+c], acc[i2]);
      }
      #pragma unroll
      for (int i2=0;i2<4;i2++) xdbl[(grp*4+i2)*40+j] = acc[i2];
    }
  }
  __syncthreads();
  // dt_proj + softplus
  for (int t=0;t<16;t++){
    double dacc = dtbv;
    #pragma unroll
    for (int r=0;r<8;r++) dacc = fma(dtw[r], xdbl[t*40+r], dacc);
    double delta = softplus_fast(dacc);
    DELTA[((size_t)db*LL + l0+t)*256 + d] = (float)delta;
  }
  for (int i=d; i<512; i+=256){
    int t = i>>5, n = i&31;
    BCb[((size_t)db*LL + l0+t)*32 + n] = (float)xdbl[t*40+8+n];
  }
}

// ---------------- 5: pure scan recurrence (power tree in NAMED SCALARS — no runtime-indexed array) ----------------
template<int PASS>
__global__ void k_scanP(const float* __restrict__ U, const float* __restrict__ DELTA,
                        const float* __restrict__ BCb, const double* __restrict__ ENT,
                        const float* __restrict__ Dv, const float* __restrict__ zm,
                        const float* __restrict__ hin,
                        float* __restrict__ S, float* __restrict__ SD,
                        float* __restrict__ yf){
  int ch = blockIdx.x, db = blockIdx.y;
  int dir = db>>2, b = db&3;
  int d = threadIdx.x;
  double cn[16];
  #pragma unroll
  for (int n=0;n<16;n++) cn[n] = ENT[n*256+d] - (double)(n+1);
  double h[16];
  if (PASS==0){
    #pragma unroll
    for (int n=0;n<16;n++) h[n]=0.0;
  } else {
    #pragma unroll
    for (int n=0;n<16;n++) h[n] = (double)hin[(((size_t)db*NCH+ch)*16+n)*256+d];
  }
  double Dd = (double)Dv[d];
  double Sd = 0.0;
  int l0 = ch*CLEN;
  const float* dp = DELTA + ((size_t)db*LL + l0)*256 + d;
  const float* up = U     + ((size_t)db*LL + l0)*256 + d;
  const float* bp = BCb   + ((size_t)db*LL + l0)*32;
  #pragma unroll 4
  for (int i=0;i<CLEN;i++){
    double dl = (double)dp[(size_t)i*256];
    double uv = (double)up[(size_t)i*256];
    if (PASS==0) Sd += dl;
    double e1 = expd_fast(-dl);
    double du = dl*uv;
    // log-depth power tree, named scalars only (compile-time indices everywhere)
    double e2 = e1*e1, e4 = e2*e2, e8 = e4*e4;
    double p1=e1,      p2=e2,      p3=e2*e1,   p4=e4;
    double p5=p1*e4,   p6=p2*e4,   p7=p3*e4,   p8=e8;
    double p9=p1*e8,   p10=p2*e8,  p11=p3*e8,  p12=p4*e8;
    double p13=p5*e8,  p14=p6*e8,  p15=p7*e8,  p16=p8*e8;
    double y = 0.0;
    #define SCAN_STEP(n, pw) { \
      double dA = (pw) * fma(-dl, cn[n], 1.0); \
      h[n] = fma(dA, h[n], du*(double)bp[i*32+(n)]); \
      if (PASS==1) y = fma(h[n], (double)bp[i*32+16+(n)], y); }
    SCAN_STEP(0,p1)  SCAN_STEP(1,p2)  SCAN_STEP(2,p3)  SCAN_STEP(3,p4)
    SCAN_STEP(4,p5)  SCAN_STEP(5,p6)  SCAN_STEP(6,p7)  SCAN_STEP(7,p8)
    SCAN_STEP(8,p9)  SCAN_STEP(9,p10) SCAN_STEP(10,p11) SCAN_STEP(11,p12)
    SCAN_STEP(12,p13) SCAN_STEP(13,p14) SCAN_STEP(14,p15) SCAN_STEP(15,p16)
    #undef SCAN_STEP
    if (PASS==1){
      int l = l0 + i;
      y = fma(Dd, uv, y);
      int lo = dir ? (LL-1-l) : l;
      y *= (double)zm[((size_t)b*LL+lo)*256+d];
      yf[((size_t)db*LL+l)*256+d] = (float)y;
    }
  }
  if (PASS==0){
    #pragma unroll
    for (int n=0;n<16;n++) S[(((size_t)db*NCH+ch)*16+n)*256+d] = (float)h[n];
    SD[((size_t)db*NCH+ch)*256+d] = (float)Sd;
  }
}

// ---------------- 6: inter-chunk combine, parallel over (n, db, d) ----------------
__global__ void k_scanB(const float* __restrict__ S, const float* __restrict__ SD,
                        const double* __restrict__ ENT, float* __restrict__ hin){
  int n = blockIdx.x, db = blockIdx.y;
  int d = threadIdx.x;
  double en = ENT[n*256+d];
  double h = 0.0;
  for (int ch=0; ch<NCH; ch++){
    size_t idx = (((size_t)db*NCH+ch)*16+n)*256+d;
    hin[idx] = (float)h;
    double Sd = (double)SD[((size_t)db*NCH+ch)*256+d];
    h = fma(expd_fast(-Sd*en), h, (double)S[idx]);   // exact chunk decay: exp(Sd*A_n)
  }
}

// ---------------- 7: fwd+rev combine, 256->128 GEMM, gate, 128->64 GEMM; 8-tok tiles ----------------
__global__ void k_out(const float* __restrict__ yf, const double* __restrict__ moutT,
                      const float* __restrict__ zo, const double* __restrict__ outT,
                      float* __restrict__ out){
  __shared__ float cs[256*13];   // [d][t], pad 13 (conflict-free writes)
  __shared__ float ys[128*13];   // [e][t], pad 13
  int blk = blockIdx.x, tid = threadIdx.x;
  int tok0 = blk*8;
  int b = tok0 / LL; int l0 = tok0 % LL;
  for (int i=tid; i<8*256; i+=256){
    int t = i>>8, d = i&255;
    int l = l0+t;
    cs[d*13+t] = yf[((size_t)b*LL + l)*256 + d] + yf[((size_t)(4+b)*LL + (LL-1-l))*256 + d];
  }
  __syncthreads();
  int e = tid & 127; int gh = tid >> 7;           // gh in {0,1}: tokens gh*4..gh*4+3
  double acc[4];
  #pragma unroll
  for (int i=0;i<4;i++) acc[i]=0.0;
  for (int d=0; d<256; d++){
    double wv = moutT[d*128+e];
    #pragma unroll
    for (int i=0;i<4;i++) acc[i] = fma(wv, (double)cs[d*13+gh*4+i], acc[i]);  // broadcast
  }
  #pragma unroll
  for (int i=0;i<4;i++){
    int t = gh*4+i;
    double zv = (double)zo[(size_t)(tok0+t)*128 + e];
    ys[e*13+t] = (float)(acc[i]*zv);
  }
  __syncthreads();
  int o = tid & 63; int g4 = tid>>6;              // g4 in 0..3: tokens g4*2, g4*2+1
  double acc2[2];
  #pragma unroll
  for (int i=0;i<2;i++) acc2[i]=0.0;
  for (int ee=0; ee<128; ee++){
    double wv = outT[ee*64+o];
    #pragma unroll
    for (int i=0;i<2;i++) acc2[i] = fma(wv, (double)ys[ee*13+g4*2+i], acc2[i]);  // broadcast
  }
  #pragma unroll
  for (int i=0;i<2;i++) out[(size_t)(tok0 + g4*2+i)*64 + o] = (float)acc2[i];
}

extern "C" void kernel_launch(void* const* d_in, const int* in_sizes, int n_in,
                              void* d_out, int out_size, void* d_ws, size_t ws_size,
                              hipStream_t stream){
  const float* x     = (const float*)d_in[0];
  const float* w_in  = (const float*)d_in[1];
  const float* c3w   = (const float*)d_in[2];
  const float* c3b   = (const float*)d_in[3];
  const float* outw  = (const float*)d_in[4];
  const float* w2    = (const float*)d_in[5];
  const float* c1w   = (const float*)d_in[6];
  const float* c1b   = (const float*)d_in[7];
  const float* xpw   = (const float*)d_in[8];
  const float* dtw   = (const float*)d_in[9];
  const float* dtb   = (const float*)d_in[10];
  const float* Alog  = (const float*)d_in[11];
  const float* Dv    = (const float*)d_in[12];
  const float* moutw = (const float*)d_in[13];
  float* ws = (float*)d_ws;
  // fp32 workspace (floats). Overlays (disjoint lifetimes):
  //   HIN overlays UPRE  (UPRE dead after k_udelta; HIN is scanB->P1)
  //   XC  inside U       (XC dead after conv3d; U written by udelta)
  //   SEQ inside DELTA   (SEQ dead after minproj; DELTA written by udelta)
  //   S   inside YF      (S dead after scanB; YF written by P1)
  float* UPRE = ws + 0;               // 2M [minproj -> udelta]
  float* HIN  = UPRE;                 // 2M [scanB -> scanP1]
  float* ZM   = ws + 2*MEG;           // 2M [minproj -> scanP1]
  float* U    = ws + 4*MEG;           // 4M [udelta -> scans]
  float* XC   = ws + 4*MEG;           // 1M [inproj -> conv3d]
  float* DELTA= ws + 8*MEG;           // 4M [udelta -> scans]
  float* SEQ  = ws + 8*MEG;           // 1M [conv3d -> minproj]
  float* BCb  = ws + 12*MEG;          // 512K [udelta -> scans]
  float* ZO   = ws + 12*MEG + 524288; // 1M [inproj -> out]
  float* YF   = ws + 13*MEG + 524288; // 4M [scanP1 -> out]
  float* Sb   = YF;                   // 2M [scanP0 -> scanB]
  float* SDb  = ws + 17*MEG + 524288; // 128K [scanP0 -> scanB]
  double* WT  = (double*)(ws + 17*MEG + 524288 + 131072); // 139,264 doubles (~75MB total)
  double* winT  = WT;
  double* w2T   = winT + 16384;
  double* xpT   = w2T + 65536;
  double* dtT   = xpT + 10240;
  double* moutT = dtT + 2048;
  double* outT  = moutT + 32768;
  double* ENT   = outT + 8192;        // exp(Alog) table [16][256]
  float* out = (float*)d_out;

  k_prep   <<<dim3(256),     dim3(256), 0, stream>>>(w_in, w2, xpw, dtw, moutw, outw, Alog,
                                                     winT, w2T, xpT, dtT, moutT, outT, ENT);
  k_inproj <<<dim3(1024),    dim3(256), 0, stream>>>(x, winT, XC, ZO);
  k_conv3d <<<dim3(512),     dim3(128), 0, stream>>>(XC, c3w, c3b, SEQ);
  k_minproj<<<dim3(1024),    dim3(256), 0, stream>>>(SEQ, w2T, UPRE, ZM);
  k_udelta <<<dim3(128,8),   dim3(256), 0, stream>>>(UPRE, c1w, c1b, xpT, dtT, dtb,
                                                     U, DELTA, BCb);
  k_scanP<0><<<dim3(NCH,8),  dim3(256), 0, stream>>>(U, DELTA, BCb, ENT, Dv, ZM,
                                                     nullptr, Sb, SDb, nullptr);
  k_scanB  <<<dim3(16,8),    dim3(256), 0, stream>>>(Sb, SDb, ENT, HIN);
  k_scanP<1><<<dim3(NCH,8),  dim3(256), 0, stream>>>(U, DELTA, BCb, ENT, Dv, ZM,
                                                     HIN, nullptr, nullptr, YF);
  k_out    <<<dim3(1024),    dim3(256), 0, stream>>>(YF, moutT, ZO, outT, out);
}

// Round 14
// 363.905 us; speedup vs baseline: 1.0699x; 1.0699x over previous
//
#include <hip/hip_runtime.h>
#include <cmath>

// Problem constants
#define B4   4
#define TT   4
#define HH   32
#define WW   16
#define LL   2048          // T*H*W
#define NCH  128           // scan chunks
#define CLEN 16            // steps per chunk
#define MEG  1048576

// ---------- fast fp64 transcendentals (rel err ~1e-13, fits 1e-9/stage budget) ----------
__device__ __forceinline__ double expd_fast(double x){
  if (x < -708.0) return 0.0;
  const double LOG2E = 1.4426950408889634074;
  const double LN2HI = 6.93147180369123816490e-01;
  const double LN2LO = 1.90821492927058770002e-10;
  double kd = rint(x*LOG2E);
  double r  = fma(-kd, LN2HI, x);
  r = fma(-kd, LN2LO, r);
  double p = 2.7557319223985888e-07;            // 1/10!
  p = fma(p, r, 2.7557319223985890e-06);
  p = fma(p, r, 2.4801587301587302e-05);
  p = fma(p, r, 1.9841269841269841e-04);
  p = fma(p, r, 1.3888888888888889e-03);
  p = fma(p, r, 8.3333333333333333e-03);
  p = fma(p, r, 4.1666666666666664e-02);
  p = fma(p, r, 1.6666666666666666e-01);
  p = fma(p, r, 5.0e-01);
  p = fma(p, r, 1.0);
  p = fma(p, r, 1.0);
  long long ki = (long long)(1023 + (int)kd) << 52;
  return p * __longlong_as_double(ki);
}
__device__ __forceinline__ double silu_fast(double a){
  return a / (1.0 + expd_fast(-a));
}
__device__ __forceinline__ double softplus_fast(double x){
  double t = expd_fast(x);
  if (t < 0.04){                                 // dominant path (dacc ~ -4.6)
    double p = 1.0/7.0;
    p = 1.0/6.0 - t*p; p = 1.0/5.0 - t*p; p = 1.0/4.0 - t*p;
    p = 1.0/3.0 - t*p; p = 1.0/2.0 - t*p; p = 1.0 - t*p;
    return t*p;                                  // log1p(t), err ~2e-11 rel
  }
  if (x > 20.0) return x;
  return log1p(t);
}

// ---------------- prep: transpose weights to fp64 + exp(Alog) table ----------------
__global__ void k_prep(const float* __restrict__ w_in, const float* __restrict__ w2,
                       const float* __restrict__ xpw, const float* __restrict__ dtw,
                       const float* __restrict__ moutw, const float* __restrict__ outw,
                       const float* __restrict__ Alog,
                       double* __restrict__ winT, double* __restrict__ w2T,
                       double* __restrict__ xpT, double* __restrict__ dtT,
                       double* __restrict__ moutT, double* __restrict__ outT,
                       double* __restrict__ ENT){
  int i = blockIdx.x*256 + threadIdx.x;
  if (i < 256*64)  winT[(i%64)*256 + i/64]   = (double)w_in[i];   // [64][256]
  if (i < 512*128) w2T[(i%128)*512 + i/128]  = (double)w2[i];     // [128][512]
  if (i < 40*256)  xpT[(i%256)*40 + i/256]   = (double)xpw[i];    // [256][40]
  if (i < 256*8)   dtT[(i%8)*256 + i/8]      = (double)dtw[i];    // [8][256]
  if (i < 128*256) moutT[(i%256)*128 + i/256]= (double)moutw[i];  // [256][128]
  if (i < 64*128)  outT[(i%128)*64 + i/128]  = (double)outw[i];   // [128][64]
  if (i < 16*256){ int n = i>>8, d = i&255; ENT[i] = exp((double)Alog[d*16+n]); } // en[n][d]
}

// ---------------- 1: in_proj (8192 tok, 64 -> 256), 8-tok tiles, transposed LDS ----------------
__global__ void k_inproj(const float* __restrict__ x, const double* __restrict__ winT,
                         float* __restrict__ xc, float* __restrict__ zo){
  __shared__ float xs[64*13];                 // [c][t], pad 13 (odd stride: conflict-free writes)
  int blk = blockIdx.x, tid = threadIdx.x;
  const float* xrow = x + (size_t)blk*8*64;
  for (int i=tid; i<8*64; i+=256){ int t=i>>6, c=i&63; xs[c*13+t] = xrow[i]; }
  __syncthreads();
  double acc[8];
  #pragma unroll
  for (int t=0;t<8;t++) acc[t]=0.0;
  for (int c=0;c<64;c++){
    double w = winT[c*256+tid];
    #pragma unroll
    for (int t=0;t<8;t++) acc[t] = fma(w, (double)xs[c*13+t], acc[t]);  // LDS broadcast
  }
  int tok0 = blk*8;
  if (tid < 128){
    #pragma unroll
    for (int t=0;t<8;t++) xc[(size_t)(tok0+t)*128 + tid] = (float)acc[t];
  } else {
    int e = tid-128;
    #pragma unroll
    for (int t=0;t<8;t++) zo[(size_t)(tok0+t)*128 + e] = (float)silu_fast(acc[t]);
  }
}

// ---------------- 2: depthwise conv3d 3x3x3 pad1 + silu ----------------
__global__ void k_conv3d(const float* __restrict__ xc, const float* __restrict__ w,
                         const float* __restrict__ bias, float* __restrict__ seq){
  int blk = blockIdx.x;
  int h = blk % HH; int t = (blk/HH) % TT; int b = blk/(HH*TT);
  int c = threadIdx.x;
  double wr[27];
  #pragma unroll
  for (int i=0;i<27;i++) wr[i] = (double)w[c*27+i];
  double bv = (double)bias[c];
  const float* base = xc + (size_t)b*LL*128;
  for (int wx=0; wx<WW; wx++){
    double acc = bv;
    #pragma unroll
    for (int dt=0; dt<3; dt++){
      int tt = t+dt-1; if (tt<0||tt>TT-1) continue;
      #pragma unroll
      for (int dh=0; dh<3; dh++){
        int h2 = h+dh-1; if (h2<0||h2>HH-1) continue;
        #pragma unroll
        for (int dw=0; dw<3; dw++){
          int w2 = wx+dw-1; if (w2<0||w2>WW-1) continue;
          int l = (tt*HH+h2)*WW+w2;
          acc = fma(wr[(dt*3+dh)*3+dw], (double)base[(size_t)l*128+c], acc);
        }
      }
    }
    int l = (t*HH+h)*WW+wx;
    seq[((size_t)b*LL+l)*128+c] = (float)silu_fast(acc);
  }
}

// ---------------- 3: m_in_proj (8192 tok, 128 -> 512), 8-tok tiles, transposed LDS ----------------
__global__ void k_minproj(const float* __restrict__ seq, const double* __restrict__ w2T,
                          float* __restrict__ upre, float* __restrict__ zm){
  __shared__ float xs[128*13];                // [c][t], pad 13
  int blk = blockIdx.x, tid = threadIdx.x;
  const float* srow = seq + (size_t)blk*8*128;
  for (int i=tid; i<8*128; i+=256){ int t=i>>7, c=i&127; xs[c*13+t] = srow[i]; }
  __syncthreads();
  double a0[8], a1[8];
  #pragma unroll
  for (int t=0;t<8;t++){a0[t]=0.0;a1[t]=0.0;}
  for (int c=0;c<128;c++){
    double w0 = w2T[c*512+tid];
    double w1 = w2T[c*512+tid+256];
    #pragma unroll
    for (int t=0;t<8;t++){
      double xv = (double)xs[c*13+t];          // LDS broadcast
      a0[t]=fma(w0,xv,a0[t]); a1[t]=fma(w1,xv,a1[t]);
    }
  }
  int tok0=blk*8;
  #pragma unroll
  for (int t=0;t<8;t++){
    upre[(size_t)(tok0+t)*256+tid] = (float)a0[t];
    zm [(size_t)(tok0+t)*256+tid] = (float)silu_fast(a1[t]);   // store gate = silu(z)
  }
}

// ---------------- 4: token-parallel front-end: conv1d+silu, x_proj, dt_proj+softplus ----------------
__global__ void k_udelta(const float* __restrict__ upre,
                         const float* __restrict__ c1w, const float* __restrict__ c1b,
                         const double* __restrict__ xpT, const double* __restrict__ dtT,
                         const float* __restrict__ dtb,
                         float* __restrict__ U, float* __restrict__ DELTA,
                         float* __restrict__ BCb){
  __shared__ float us[16*256];
  __shared__ double xdbl[16*40];
  int tile = blockIdx.x, db = blockIdx.y;
  int dir = db>>2, b = db&3;
  int d = threadIdx.x;
  double w0=(double)c1w[d*4+0], w1=(double)c1w[d*4+1], w2=(double)c1w[d*4+2], w3=(double)c1w[d*4+3];
  double cbv=(double)c1b[d];
  double dtbv=(double)dtb[d];
  double dtw[8];
  #pragma unroll
  for (int r=0;r<8;r++) dtw[r] = dtT[r*256+d];
  int l0 = tile*16;
  auto src = [&](int l)->double{
    if (l < 0) return 0.0;
    int lo = dir ? (LL-1-l) : l;
    return (double)upre[((size_t)b*LL+lo)*256+d];
  };
  double x0=src(l0-3), x1=src(l0-2), x2=src(l0-1);
  for (int i=0;i<16;i++){
    double x3 = src(l0+i);
    double a = cbv + w0*x0 + w1*x1 + w2*x2 + w3*x3;
    float uv = (float)silu_fast(a);
    us[i*256+d] = uv;
    U[((size_t)db*LL + l0+i)*256 + d] = uv;
    x0=x1; x1=x2; x2=x3;
  }
  __syncthreads();
  // x_proj GEMM (256 -> 40) for 16 tokens
  {
    int j = d & 63, grp = d >> 6;
    if (j < 40){
      double acc[4]={0.0,0.0,0.0,0.0};
      for (int c=0;c<256;c++){
        double wv = xpT[c*40+j];
        #pragma unroll
        for (int i2=0;i2<4;i2++) acc[i2] = fma(wv, (double)us[(grp*4+i2)*256+c], acc[i2]);
      }
      #pragma unroll
      for (int i2=0;i2<4;i2++) xdbl[(grp*4+i2)*40+j] = acc[i2];
    }
  }
  __syncthreads();
  // dt_proj + softplus
  for (int t=0;t<16;t++){
    double dacc = dtbv;
    #pragma unroll
    for (int r=0;r<8;r++) dacc = fma(dtw[r], xdbl[t*40+r], dacc);
    double delta = softplus_fast(dacc);
    DELTA[((size_t)db*LL + l0+t)*256 + d] = (float)delta;
  }
  for (int i=d; i<512; i+=256){
    int t = i>>5, n = i&31;
    BCb[((size_t)db*LL + l0+t)*32 + n] = (float)xdbl[t*40+8+n];
  }
}

// ---------------- 5: pure scan recurrence (serial pw chain — R11-proven body) ----------------
// PASS 0: from h=0, emit chunk state S + sum-of-delta SD.
// PASS 1: from hin(=S after scanB), atomicAdd gated y into combined YC[b][lo].
template<int PASS>
__global__ void k_scanP(const float* __restrict__ U, const float* __restrict__ DELTA,
                        const float* __restrict__ BCb, const double* __restrict__ ENT,
                        const float* __restrict__ Dv, const float* __restrict__ zm,
                        const float* __restrict__ hin,
                        float* __restrict__ S, float* __restrict__ SD,
                        float* __restrict__ yc){
  int ch = blockIdx.x, db = blockIdx.y;
  int dir = db>>2, b = db&3;
  int d = threadIdx.x;
  double cn[16];
  #pragma unroll
  for (int n=0;n<16;n++) cn[n] = ENT[n*256+d] - (double)(n+1);
  double h[16];
  if (PASS==0){
    #pragma unroll
    for (int n=0;n<16;n++) h[n]=0.0;
  } else {
    #pragma unroll
    for (int n=0;n<16;n++) h[n] = (double)hin[(((size_t)db*NCH+ch)*16+n)*256+d];
  }
  double Dd = (double)Dv[d];
  double Sd = 0.0;
  int l0 = ch*CLEN;
  const float* dp = DELTA + ((size_t)db*LL + l0)*256 + d;
  const float* up = U     + ((size_t)db*LL + l0)*256 + d;
  const float* bp = BCb   + ((size_t)db*LL + l0)*32;
  #pragma unroll 4
  for (int i=0;i<CLEN;i++){
    double dl = (double)dp[(size_t)i*256];
    double uv = (double)up[(size_t)i*256];
    if (PASS==0) Sd += dl;
    double e1 = expd_fast(-dl);
    double du = dl*uv;
    double pw = 1.0;
    double y = 0.0;
    #pragma unroll
    for (int n=0;n<16;n++){
      pw *= e1;
      double dA = pw * fma(-dl, cn[n], 1.0);    // exp(-dl*en) to fp64 accuracy
      h[n] = fma(dA, h[n], du*(double)bp[i*32+n]);
      if (PASS==1) y = fma(h[n], (double)bp[i*32+16+n], y);
    }
    if (PASS==1){
      int l = l0 + i;
      y = fma(Dd, uv, y);
      int lo = dir ? (LL-1-l) : l;
      y *= (double)zm[((size_t)b*LL+lo)*256+d];
      // exactly 2 contributions (fwd+rev) per cell -> commutative, bit-deterministic
      atomicAdd(&yc[((size_t)b*LL+lo)*256+d], (float)y);
    }
  }
  if (PASS==0){
    #pragma unroll
    for (int n=0;n<16;n++) S[(((size_t)db*NCH+ch)*16+n)*256+d] = (float)h[n];
    SD[((size_t)db*NCH+ch)*256+d] = (float)Sd;
  }
}

// ---------------- 6: inter-chunk combine, IN PLACE (S becomes h_init per chunk) ----------------
__global__ void k_scanB(float* __restrict__ S, const float* __restrict__ SD,
                        const double* __restrict__ ENT){
  int n = blockIdx.x, db = blockIdx.y;
  int d = threadIdx.x;
  double en = ENT[n*256+d];
  double h = 0.0;
  for (int ch=0; ch<NCH; ch++){
    size_t idx = (((size_t)db*NCH+ch)*16+n)*256+d;
    double Sl = (double)S[idx];
    S[idx] = (float)h;                                       // h_init for chunk ch
    double Sd = (double)SD[((size_t)db*NCH+ch)*256+d];
    h = fma(expd_fast(-Sd*en), h, Sl);                       // exact chunk decay exp(Sd*A_n)
  }
}

// ---------------- 7: out_proj 256->128, gate, 128->64; 8-tok tiles, combined-y input ----------------
__global__ void k_out(const float* __restrict__ yc, const double* __restrict__ moutT,
                      const float* __restrict__ zo, const double* __restrict__ outT,
                      float* __restrict__ out){
  __shared__ float cs[256*13];   // [d][t], pad 13 (conflict-free writes)
  __shared__ float ys[128*13];   // [e][t], pad 13
  int blk = blockIdx.x, tid = threadIdx.x;
  int tok0 = blk*8;
  for (int i=tid; i<8*256; i+=256){
    int t = i>>8, d = i&255;
    cs[d*13+t] = yc[(size_t)(tok0+t)*256 + d];
  }
  __syncthreads();
  int e = tid & 127; int gh = tid >> 7;           // gh in {0,1}: tokens gh*4..gh*4+3
  double acc[4];
  #pragma unroll
  for (int i=0;i<4;i++) acc[i]=0.0;
  for (int d=0; d<256; d++){
    double wv = moutT[d*128+e];
    #pragma unroll
    for (int i=0;i<4;i++) acc[i] = fma(wv, (double)cs[d*13+gh*4+i], acc[i]);  // broadcast
  }
  #pragma unroll
  for (int i=0;i<4;i++){
    int t = gh*4+i;
    double zv = (double)zo[(size_t)(tok0+t)*128 + e];
    ys[e*13+t] = (float)(acc[i]*zv);
  }
  __syncthreads();
  int o = tid & 63; int g4 = tid>>6;              // g4 in 0..3: tokens g4*2, g4*2+1
  double acc2[2];
  #pragma unroll
  for (int i=0;i<2;i++) acc2[i]=0.0;
  for (int ee=0; ee<128; ee++){
    double wv = outT[ee*64+o];
    #pragma unroll
    for (int i=0;i<2;i++) acc2[i] = fma(wv, (double)ys[ee*13+g4*2+i], acc2[i]);  // broadcast
  }
  #pragma unroll
  for (int i=0;i<2;i++) out[(size_t)(tok0 + g4*2+i)*64 + o] = (float)acc2[i];
}

extern "C" void kernel_launch(void* const* d_in, const int* in_sizes, int n_in,
                              void* d_out, int out_size, void* d_ws, size_t ws_size,
                              hipStream_t stream){
  const float* x     = (const float*)d_in[0];
  const float* w_in  = (const float*)d_in[1];
  const float* c3w   = (const float*)d_in[2];
  const float* c3b   = (const float*)d_in[3];
  const float* outw  = (const float*)d_in[4];
  const float* w2    = (const float*)d_in[5];
  const float* c1w   = (const float*)d_in[6];
  const float* c1b   = (const float*)d_in[7];
  const float* xpw   = (const float*)d_in[8];
  const float* dtw   = (const float*)d_in[9];
  const float* dtb   = (const float*)d_in[10];
  const float* Alog  = (const float*)d_in[11];
  const float* Dv    = (const float*)d_in[12];
  const float* moutw = (const float*)d_in[13];
  float* ws = (float*)d_ws;
  // fp32 workspace (floats), ~80MB. Overlays (disjoint lifetimes):
  //   XC  inside U       (XC dead after conv3d; U written by udelta)
  //   SEQ inside DELTA   (SEQ dead after minproj; DELTA written by udelta)
  //   S rewritten in place by scanB (chunk state -> chunk h_init)
  float* UPRE = ws + 0;               // 2M   [minproj -> udelta]
  float* ZM   = ws + 2*MEG;           // 2M   [minproj -> scanP1] (silu(z))
  float* U    = ws + 4*MEG;           // 4M   [udelta -> scans]
  float* XC   = ws + 4*MEG;           // 1M   [inproj -> conv3d]
  float* DELTA= ws + 8*MEG;           // 4M   [udelta -> scans]
  float* SEQ  = ws + 8*MEG;           // 1M   [conv3d -> minproj]
  float* BCb  = ws + 12*MEG;          // 512K [udelta -> scans]
  float* ZO   = ws + 12*MEG + 524288; // 1M   [inproj -> out] (silu(z))
  float* YC   = ws + 13*MEG + 524288; // 2M   [scanP1 atomic -> out] (fwd+rev combined)
  float* Sb   = ws + 15*MEG + 524288; // 4M   [scanP0 -> scanB(inplace) -> scanP1]
  float* SDb  = ws + 19*MEG + 524288; // 256K [scanP0 -> scanB]
  double* WT  = (double*)(ws + 19*MEG + 524288 + 262144); // 139,264 doubles
  double* winT  = WT;
  double* w2T   = winT + 16384;
  double* xpT   = w2T + 65536;
  double* dtT   = xpT + 10240;
  double* moutT = dtT + 2048;
  double* outT  = moutT + 32768;
  double* ENT   = outT + 8192;        // exp(Alog) table [16][256]
  float* out = (float*)d_out;

  k_prep   <<<dim3(256),     dim3(256), 0, stream>>>(w_in, w2, xpw, dtw, moutw, outw, Alog,
                                                     winT, w2T, xpT, dtT, moutT, outT, ENT);
  hipMemsetAsync(YC, 0, 2*MEG*sizeof(float), stream);   // zero combined-y accumulator
  k_inproj <<<dim3(1024),    dim3(256), 0, stream>>>(x, winT, XC, ZO);
  k_conv3d <<<dim3(512),     dim3(128), 0, stream>>>(XC, c3w, c3b, SEQ);
  k_minproj<<<dim3(1024),    dim3(256), 0, stream>>>(SEQ, w2T, UPRE, ZM);
  k_udelta <<<dim3(128,8),   dim3(256), 0, stream>>>(UPRE, c1w, c1b, xpT, dtT, dtb,
                                                     U, DELTA, BCb);
  k_scanP<0><<<dim3(NCH,8),  dim3(256), 0, stream>>>(U, DELTA, BCb, ENT, Dv, ZM,
                                                     nullptr, Sb, SDb, nullptr);
  k_scanB  <<<dim3(16,8),    dim3(256), 0, stream>>>(Sb, SDb, ENT);
  k_scanP<1><<<dim3(NCH,8),  dim3(256), 0, stream>>>(U, DELTA, BCb, ENT, Dv, ZM,
                                                     Sb, nullptr, nullptr, YC);
  k_out    <<<dim3(1024),    dim3(256), 0, stream>>>(YC, moutT, ZO, outT, out);
}

// Round 15
// 356.779 us; speedup vs baseline: 1.0913x; 1.0200x over previous
//
#include <hip/hip_runtime.h>
#include <cmath>

// Problem constants
#define B4   4
#define TT   4
#define HH   32
#define WW   16
#define LL   2048          // T*H*W
#define NCH  128           // scan chunks
#define CLEN 16            // steps per chunk
#define MEG  1048576

// ---------- fast fp64 transcendentals (rel err ~1e-13, fits 1e-9/stage budget) ----------
__device__ __forceinline__ double expd_fast(double x){
  if (x < -708.0) return 0.0;
  const double LOG2E = 1.4426950408889634074;
  const double LN2HI = 6.93147180369123816490e-01;
  const double LN2LO = 1.90821492927058770002e-10;
  double kd = rint(x*LOG2E);
  double r  = fma(-kd, LN2HI, x);
  r = fma(-kd, LN2LO, r);
  double p = 2.7557319223985888e-07;            // 1/10!
  p = fma(p, r, 2.7557319223985890e-06);
  p = fma(p, r, 2.4801587301587302e-05);
  p = fma(p, r, 1.9841269841269841e-04);
  p = fma(p, r, 1.3888888888888889e-03);
  p = fma(p, r, 8.3333333333333333e-03);
  p = fma(p, r, 4.1666666666666664e-02);
  p = fma(p, r, 1.6666666666666666e-01);
  p = fma(p, r, 5.0e-01);
  p = fma(p, r, 1.0);
  p = fma(p, r, 1.0);
  long long ki = (long long)(1023 + (int)kd) << 52;
  return p * __longlong_as_double(ki);
}
__device__ __forceinline__ double silu_fast(double a){
  return a / (1.0 + expd_fast(-a));
}
__device__ __forceinline__ double softplus_fast(double x){
  double t = expd_fast(x);
  if (t < 0.04){                                 // dominant path (dacc ~ -4.6)
    double p = 1.0/7.0;
    p = 1.0/6.0 - t*p; p = 1.0/5.0 - t*p; p = 1.0/4.0 - t*p;
    p = 1.0/3.0 - t*p; p = 1.0/2.0 - t*p; p = 1.0 - t*p;
    return t*p;                                  // log1p(t), err ~2e-11 rel
  }
  if (x > 20.0) return x;
  return log1p(t);
}

// ---------------- prep: transpose weights to fp64 + exp(Alog) table ----------------
__global__ void k_prep(const float* __restrict__ w_in, const float* __restrict__ w2,
                       const float* __restrict__ xpw, const float* __restrict__ dtw,
                       const float* __restrict__ moutw, const float* __restrict__ outw,
                       const float* __restrict__ Alog,
                       double* __restrict__ winT, double* __restrict__ w2T,
                       double* __restrict__ xpT, double* __restrict__ dtT,
                       double* __restrict__ moutT, double* __restrict__ outT,
                       double* __restrict__ ENT){
  int i = blockIdx.x*256 + threadIdx.x;
  if (i < 256*64)  winT[(i%64)*256 + i/64]   = (double)w_in[i];   // [64][256]
  if (i < 512*128) w2T[(i%128)*512 + i/128]  = (double)w2[i];     // [128][512]
  if (i < 40*256)  xpT[(i%256)*40 + i/256]   = (double)xpw[i];    // [256][40]
  if (i < 256*8)   dtT[(i%8)*256 + i/8]      = (double)dtw[i];    // [8][256]
  if (i < 128*256) moutT[(i%256)*128 + i/256]= (double)moutw[i];  // [256][128]
  if (i < 64*128)  outT[(i%128)*64 + i/128]  = (double)outw[i];   // [128][64]
  if (i < 16*256){ int n = i>>8, d = i&255; ENT[i] = exp((double)Alog[d*16+n]); } // en[n][d]
}

// ---------------- 1: in_proj (8192 tok, 64 -> 256), 8-tok tiles, transposed LDS ----------------
__global__ void k_inproj(const float* __restrict__ x, const double* __restrict__ winT,
                         float* __restrict__ xc, float* __restrict__ zo){
  __shared__ float xs[64*13];                 // [c][t], pad 13 (odd stride: conflict-free writes)
  int blk = blockIdx.x, tid = threadIdx.x;
  const float* xrow = x + (size_t)blk*8*64;
  for (int i=tid; i<8*64; i+=256){ int t=i>>6, c=i&63; xs[c*13+t] = xrow[i]; }
  __syncthreads();
  double acc[8];
  #pragma unroll
  for (int t=0;t<8;t++) acc[t]=0.0;
  for (int c=0;c<64;c++){
    double w = winT[c*256+tid];
    #pragma unroll
    for (int t=0;t<8;t++) acc[t] = fma(w, (double)xs[c*13+t], acc[t]);  // LDS broadcast
  }
  int tok0 = blk*8;
  if (tid < 128){
    #pragma unroll
    for (int t=0;t<8;t++) xc[(size_t)(tok0+t)*128 + tid] = (float)acc[t];
  } else {
    int e = tid-128;
    #pragma unroll
    for (int t=0;t<8;t++) zo[(size_t)(tok0+t)*128 + e] = (float)silu_fast(acc[t]);
  }
}

// ---------------- 2: depthwise conv3d 3x3x3 pad1 + silu (256 thr: c x 2 wx-halves) ----------------
__global__ void k_conv3d(const float* __restrict__ xc, const float* __restrict__ w,
                         const float* __restrict__ bias, float* __restrict__ seq){
  int blk = blockIdx.x;
  int h = blk % HH; int t = (blk/HH) % TT; int b = blk/(HH*TT);
  int c = threadIdx.x & 127;
  int wh = threadIdx.x >> 7;                 // 0/1: wx half
  double wr[27];
  #pragma unroll
  for (int i=0;i<27;i++) wr[i] = (double)w[c*27+i];
  double bv = (double)bias[c];
  const float* base = xc + (size_t)b*LL*128;
  for (int wx=wh*8; wx<wh*8+8; wx++){
    double acc = bv;
    #pragma unroll
    for (int dt=0; dt<3; dt++){
      int tt = t+dt-1; if (tt<0||tt>TT-1) continue;
      #pragma unroll
      for (int dh=0; dh<3; dh++){
        int h2 = h+dh-1; if (h2<0||h2>HH-1) continue;
        #pragma unroll
        for (int dw=0; dw<3; dw++){
          int w2 = wx+dw-1; if (w2<0||w2>WW-1) continue;
          int l = (tt*HH+h2)*WW+w2;
          acc = fma(wr[(dt*3+dh)*3+dw], (double)base[(size_t)l*128+c], acc);
        }
      }
    }
    int l = (t*HH+h)*WW+wx;
    seq[((size_t)b*LL+l)*128+c] = (float)silu_fast(acc);
  }
}

// ---------------- 3: m_in_proj (8192 tok, 128 -> 512), 8-tok tiles, transposed LDS ----------------
__global__ void k_minproj(const float* __restrict__ seq, const double* __restrict__ w2T,
                          float* __restrict__ upre, float* __restrict__ zm){
  __shared__ float xs[128*13];                // [c][t], pad 13
  int blk = blockIdx.x, tid = threadIdx.x;
  const float* srow = seq + (size_t)blk*8*128;
  for (int i=tid; i<8*128; i+=256){ int t=i>>7, c=i&127; xs[c*13+t] = srow[i]; }
  __syncthreads();
  double a0[8], a1[8];
  #pragma unroll
  for (int t=0;t<8;t++){a0[t]=0.0;a1[t]=0.0;}
  for (int c=0;c<128;c++){
    double w0 = w2T[c*512+tid];
    double w1 = w2T[c*512+tid+256];
    #pragma unroll
    for (int t=0;t<8;t++){
      double xv = (double)xs[c*13+t];          // LDS broadcast
      a0[t]=fma(w0,xv,a0[t]); a1[t]=fma(w1,xv,a1[t]);
    }
  }
  int tok0=blk*8;
  #pragma unroll
  for (int t=0;t<8;t++){
    upre[(size_t)(tok0+t)*256+tid] = (float)a0[t];
    zm [(size_t)(tok0+t)*256+tid] = (float)silu_fast(a1[t]);   // store gate = silu(z)
  }
}

// ---------------- 4: token-parallel front-end: conv1d+silu, x_proj, dt_proj+softplus ----------------
__global__ void k_udelta(const float* __restrict__ upre,
                         const float* __restrict__ c1w, const float* __restrict__ c1b,
                         const double* __restrict__ xpT, const double* __restrict__ dtT,
                         const float* __restrict__ dtb,
                         float* __restrict__ U, float* __restrict__ DELTA,
                         float* __restrict__ BCb){
  __shared__ float us[16*256];
  __shared__ double xdbl[16*40];
  int tile = blockIdx.x, db = blockIdx.y;
  int dir = db>>2, b = db&3;
  int d = threadIdx.x;
  double w0=(double)c1w[d*4+0], w1=(double)c1w[d*4+1], w2=(double)c1w[d*4+2], w3=(double)c1w[d*4+3];
  double cbv=(double)c1b[d];
  double dtbv=(double)dtb[d];
  double dtw[8];
  #pragma unroll
  for (int r=0;r<8;r++) dtw[r] = dtT[r*256+d];
  int l0 = tile*16;
  auto src = [&](int l)->double{
    if (l < 0) return 0.0;
    int lo = dir ? (LL-1-l) : l;
    return (double)upre[((size_t)b*LL+lo)*256+d];
  };
  double x0=src(l0-3), x1=src(l0-2), x2=src(l0-1);
  for (int i=0;i<16;i++){
    double x3 = src(l0+i);
    double a = cbv + w0*x0 + w1*x1 + w2*x2 + w3*x3;
    float uv = (float)silu_fast(a);
    us[i*256+d] = uv;
    U[((size_t)db*LL + l0+i)*256 + d] = uv;
    x0=x1; x1=x2; x2=x3;
  }
  __syncthreads();
  // x_proj GEMM (256 -> 40) for 16 tokens
  {
    int j = d & 63, grp = d >> 6;
    if (j < 40){
      double acc[4]={0.0,0.0,0.0,0.0};
      for (int c=0;c<256;c++){
        double wv = xpT[c*40+j];
        #pragma unroll
        for (int i2=0;i2<4;i2++) acc[i2] = fma(wv, (double)us[(grp*4+i2)*256+c], acc[i2]);
      }
      #pragma unroll
      for (int i2=0;i2<4;i2++) xdbl[(grp*4+i2)*40+j] = acc[i2];
    }
  }
  __syncthreads();
  // dt_proj + softplus
  for (int t=0;t<16;t++){
    double dacc = dtbv;
    #pragma unroll
    for (int r=0;r<8;r++) dacc = fma(dtw[r], xdbl[t*40+r], dacc);
    double delta = softplus_fast(dacc);
    DELTA[((size_t)db*LL + l0+t)*256 + d] = (float)delta;
  }
  for (int i=d; i<512; i+=256){
    int t = i>>5, n = i&31;
    BCb[((size_t)db*LL + l0+t)*32 + n] = (float)xdbl[t*40+8+n];
  }
}

// ---------------- 5: pure scan recurrence (serial pw chain — R11-proven body) ----------------
// PASS 0: from h=0, emit chunk state S + sum-of-delta SD.
// PASS 1: from hin(=S after scanB), atomicAdd gated y into combined YC[b][lo].
template<int PASS>
__global__ void k_scanP(const float* __restrict__ U, const float* __restrict__ DELTA,
                        const float* __restrict__ BCb, const double* __restrict__ ENT,
                        const float* __restrict__ Dv, const float* __restrict__ zm,
                        const float* __restrict__ hin,
                        float* __restrict__ S, float* __restrict__ SD,
                        float* __restrict__ yc){
  int ch = blockIdx.x, db = blockIdx.y;
  int dir = db>>2, b = db&3;
  int d = threadIdx.x;
  double cn[16];
  #pragma unroll
  for (int n=0;n<16;n++) cn[n] = ENT[n*256+d] - (double)(n+1);
  double h[16];
  if (PASS==0){
    #pragma unroll
    for (int n=0;n<16;n++) h[n]=0.0;
  } else {
    #pragma unroll
    for (int n=0;n<16;n++) h[n] = (double)hin[(((size_t)db*NCH+ch)*16+n)*256+d];
  }
  double Dd = (double)Dv[d];
  double Sd = 0.0;
  int l0 = ch*CLEN;
  const float* dp = DELTA + ((size_t)db*LL + l0)*256 + d;
  const float* up = U     + ((size_t)db*LL + l0)*256 + d;
  const float* bp = BCb   + ((size_t)db*LL + l0)*32;
  #pragma unroll 4
  for (int i=0;i<CLEN;i++){
    double dl = (double)dp[(size_t)i*256];
    double uv = (double)up[(size_t)i*256];
    if (PASS==0) Sd += dl;
    double e1 = expd_fast(-dl);
    double du = dl*uv;
    double pw = 1.0;
    double y = 0.0;
    #pragma unroll
    for (int n=0;n<16;n++){
      pw *= e1;
      double dA = pw * fma(-dl, cn[n], 1.0);    // exp(-dl*en) to fp64 accuracy
      h[n] = fma(dA, h[n], du*(double)bp[i*32+n]);
      if (PASS==1) y = fma(h[n], (double)bp[i*32+16+n], y);
    }
    if (PASS==1){
      int l = l0 + i;
      y = fma(Dd, uv, y);
      int lo = dir ? (LL-1-l) : l;
      y *= (double)zm[((size_t)b*LL+lo)*256+d];
      // exactly 2 contributions (fwd+rev) per cell -> commutative, bit-deterministic
      atomicAdd(&yc[((size_t)b*LL+lo)*256+d], (float)y);
    }
  }
  if (PASS==0){
    #pragma unroll
    for (int n=0;n<16;n++) S[(((size_t)db*NCH+ch)*16+n)*256+d] = (float)h[n];
    SD[((size_t)db*NCH+ch)*256+d] = (float)Sd;
  }
}

// ---------------- 6: inter-chunk combine, IN PLACE (S becomes h_init per chunk) ----------------
__global__ void k_scanB(float* __restrict__ S, const float* __restrict__ SD,
                        const double* __restrict__ ENT){
  int n = blockIdx.x, db = blockIdx.y;
  int d = threadIdx.x;
  double en = ENT[n*256+d];
  double h = 0.0;
  for (int ch=0; ch<NCH; ch++){
    size_t idx = (((size_t)db*NCH+ch)*16+n)*256+d;
    double Sl = (double)S[idx];
    S[idx] = (float)h;                                       // h_init for chunk ch
    double Sd = (double)SD[((size_t)db*NCH+ch)*256+d];
    h = fma(expd_fast(-Sd*en), h, Sl);                       // exact chunk decay exp(Sd*A_n)
  }
}

// ---------------- 7: out_proj 256->128, gate, 128->64; 16-tok tiles, b128 LDS reads ----------------
__global__ void k_out(const float* __restrict__ yc, const double* __restrict__ moutT,
                      const float* __restrict__ zo, const double* __restrict__ outT,
                      float* __restrict__ out){
  __shared__ float4 cs4[256*4];   // cs[d][16] floats, 64B rows -> aligned b128 reads
  __shared__ float4 ys4[128*4];   // ys[e][16]
  float* cs = (float*)cs4;
  float* ys = (float*)ys4;
  int blk = blockIdx.x, tid = threadIdx.x;
  int tok0 = blk*16;
  for (int i=tid; i<16*256; i+=256){
    int t = i>>8, d = i&255;
    cs[d*16+t] = yc[(size_t)(tok0+t)*256 + d];
  }
  __syncthreads();
  // GEMM1: 256 -> 128, thread = (e, gh): tokens gh*8..gh*8+7
  int e = tid & 127; int gh = tid >> 7;
  double acc[8];
  #pragma unroll
  for (int i=0;i<8;i++) acc[i]=0.0;
  for (int d=0; d<256; d++){
    double wv = moutT[d*128+e];
    float4 fa = cs4[d*4 + gh*2 + 0];
    float4 fb = cs4[d*4 + gh*2 + 1];
    acc[0] = fma(wv, (double)fa.x, acc[0]);
    acc[1] = fma(wv, (double)fa.y, acc[1]);
    acc[2] = fma(wv, (double)fa.z, acc[2]);
    acc[3] = fma(wv, (double)fa.w, acc[3]);
    acc[4] = fma(wv, (double)fb.x, acc[4]);
    acc[5] = fma(wv, (double)fb.y, acc[5]);
    acc[6] = fma(wv, (double)fb.z, acc[6]);
    acc[7] = fma(wv, (double)fb.w, acc[7]);
  }
  #pragma unroll
  for (int i=0;i<8;i++){
    int t = gh*8+i;
    double zv = (double)zo[(size_t)(tok0+t)*128 + e];
    ys[e*16+t] = (float)(acc[i]*zv);
  }
  __syncthreads();
  // GEMM2: 128 -> 64, thread = (o, g4): tokens g4*4..g4*4+3
  int o = tid & 63; int g4 = tid>>6;
  double acc2[4];
  #pragma unroll
  for (int i=0;i<4;i++) acc2[i]=0.0;
  for (int ee=0; ee<128; ee++){
    double wv = outT[ee*64+o];
    float4 f = ys4[ee*4 + g4];
    acc2[0] = fma(wv, (double)f.x, acc2[0]);
    acc2[1] = fma(wv, (double)f.y, acc2[1]);
    acc2[2] = fma(wv, (double)f.z, acc2[2]);
    acc2[3] = fma(wv, (double)f.w, acc2[3]);
  }
  #pragma unroll
  for (int i=0;i<4;i++) out[(size_t)(tok0 + g4*4+i)*64 + o] = (float)acc2[i];
}

extern "C" void kernel_launch(void* const* d_in, const int* in_sizes, int n_in,
                              void* d_out, int out_size, void* d_ws, size_t ws_size,
                              hipStream_t stream){
  const float* x     = (const float*)d_in[0];
  const float* w_in  = (const float*)d_in[1];
  const float* c3w   = (const float*)d_in[2];
  const float* c3b   = (const float*)d_in[3];
  const float* outw  = (const float*)d_in[4];
  const float* w2    = (const float*)d_in[5];
  const float* c1w   = (const float*)d_in[6];
  const float* c1b   = (const float*)d_in[7];
  const float* xpw   = (const float*)d_in[8];
  const float* dtw   = (const float*)d_in[9];
  const float* dtb   = (const float*)d_in[10];
  const float* Alog  = (const float*)d_in[11];
  const float* Dv    = (const float*)d_in[12];
  const float* moutw = (const float*)d_in[13];
  float* ws = (float*)d_ws;
  // fp32 workspace (floats), ~80MB. Overlays (disjoint lifetimes):
  //   XC  inside U       (XC dead after conv3d; U written by udelta)
  //   SEQ inside DELTA   (SEQ dead after minproj; DELTA written by udelta)
  //   S rewritten in place by scanB (chunk state -> chunk h_init)
  float* UPRE = ws + 0;               // 2M   [minproj -> udelta]
  float* ZM   = ws + 2*MEG;           // 2M   [minproj -> scanP1] (silu(z))
  float* U    = ws + 4*MEG;           // 4M   [udelta -> scans]
  float* XC   = ws + 4*MEG;           // 1M   [inproj -> conv3d]
  float* DELTA= ws + 8*MEG;           // 4M   [udelta -> scans]
  float* SEQ  = ws + 8*MEG;           // 1M   [conv3d -> minproj]
  float* BCb  = ws + 12*MEG;          // 512K [udelta -> scans]
  float* ZO   = ws + 12*MEG + 524288; // 1M   [inproj -> out] (silu(z))
  float* YC   = ws + 13*MEG + 524288; // 2M   [scanP1 atomic -> out] (fwd+rev combined)
  float* Sb   = ws + 15*MEG + 524288; // 4M   [scanP0 -> scanB(inplace) -> scanP1]
  float* SDb  = ws + 19*MEG + 524288; // 256K [scanP0 -> scanB]
  double* WT  = (double*)(ws + 19*MEG + 524288 + 262144); // 139,264 doubles
  double* winT  = WT;
  double* w2T   = winT + 16384;
  double* xpT   = w2T + 65536;
  double* dtT   = xpT + 10240;
  double* moutT = dtT + 2048;
  double* outT  = moutT + 32768;
  double* ENT   = outT + 8192;        // exp(Alog) table [16][256]
  float* out = (float*)d_out;

  k_prep   <<<dim3(256),     dim3(256), 0, stream>>>(w_in, w2, xpw, dtw, moutw, outw, Alog,
                                                     winT, w2T, xpT, dtT, moutT, outT, ENT);
  hipMemsetAsync(YC, 0, 2*MEG*sizeof(float), stream);   // zero combined-y accumulator
  k_inproj <<<dim3(1024),    dim3(256), 0, stream>>>(x, winT, XC, ZO);
  k_conv3d <<<dim3(512),     dim3(256), 0, stream>>>(XC, c3w, c3b, SEQ);
  k_minproj<<<dim3(1024),    dim3(256), 0, stream>>>(SEQ, w2T, UPRE, ZM);
  k_udelta <<<dim3(128,8),   dim3(256), 0, stream>>>(UPRE, c1w, c1b, xpT, dtT, dtb,
                                                     U, DELTA, BCb);
  k_scanP<0><<<dim3(NCH,8),  dim3(256), 0, stream>>>(U, DELTA, BCb, ENT, Dv, ZM,
                                                     nullptr, Sb, SDb, nullptr);
  k_scanB  <<<dim3(16,8),    dim3(256), 0, stream>>>(Sb, SDb, ENT);
  k_scanP<1><<<dim3(NCH,8),  dim3(256), 0, stream>>>(U, DELTA, BCb, ENT, Dv, ZM,
                                                     Sb, nullptr, nullptr, YC);
  k_out    <<<dim3(512),     dim3(256), 0, stream>>>(YC, moutT, ZO, outT, out);
}